// Round 5
// baseline (35.464 us; speedup 1.0000x reference)
//
#include <hip/hip_runtime.h>

// eTofts model: B=8, T=60, H=W=256.
//   params[B,3,H,W], Cp[B,T], S0[B,1,H,W], T1[B,1,H,W] -> St[B,T,H,W] fp32
// True traffic: 125.8 MB out + ~10.5 MB in => ~18-20 us floor at ~7 TB/s HBM.
//
// R4 lesson: 4KB-contiguous nt stores ~neutral (33.1 us). Fill kernel evidence:
// plain 1KB-wave stores, FETCH~0 => no RFO on gfx950. nt = no-allocate forces
// output to HBM; but 126 MB output FITS the 256 MB L3 -> plain allocating
// stores may complete at L3 speed. Single flip this round: nt -> plain.

#define N_TIME 60
#define HW (256 * 256)
#define CHUNKS 4
#define CHUNK_LEN (N_TIME / CHUNKS)   // 15
#define PXB 4096                      // pixels per block (256 thr * 16 px)

typedef float f32x4 __attribute__((ext_vector_type(4)));

__global__ __launch_bounds__(256, 2) void etofts_kernel(
    const float* __restrict__ params,  // [B,3,H,W]
    const float* __restrict__ Cp,      // [B,T]
    const float* __restrict__ S0,      // [B,1,H,W]
    const float* __restrict__ T1,      // [B,1,H,W]
    float* __restrict__ out)           // [B,T,H,W]
{
    const float DT     = 5.0f;
    const float TR     = 5.0f;
    const float EPS    = 1e-8f;
    const float COS_FA = 0.9848077530122081f;            // cos(10 deg)
    const float QC2    = 0.0225f * 1.4426950408889634f;  // (R1*TR/1000)*log2(e)

    // 512 blocks: b = bx>>6 (64/batch), chunk = (bx>>4)&3, blk = bx&15.
    const int bx    = blockIdx.x;
    const int b     = bx >> 6;
    const int chunk = (bx >> 4) & 3;
    const int blk   = bx & 15;

    // Wave w owns a 4 KB contiguous span per frame: px = blk*4096 + w*1024
    //  + q*256 + lane*4, q = 0..3.  Store instr (fixed q) = 1 KB contiguous.
    const int w    = threadIdx.x >> 6;
    const int lane = threadIdx.x & 63;
    const int pixw = blk * PXB + w * 1024 + lane * 4;

    const float* p0 = params + ((size_t)b * 3 + 0) * HW + pixw;
    const float* p1 = params + ((size_t)b * 3 + 1) * HW + pixw;
    const float* p2 = params + ((size_t)b * 3 + 2) * HW + pixw;
    const float* ps = S0 + (size_t)b * HW + pixw;
    const float* pt = T1 + (size_t)b * HW + pixw;

    float Kt[16], vp[16], decay[16], Ce[16], eP[16], Kc[16], d0[16], d1[16];

#pragma unroll
    for (int q = 0; q < 4; ++q) {
        const float4 kt4 = *reinterpret_cast<const float4*>(p0 + q * 256);
        const float4 vp4 = *reinterpret_cast<const float4*>(p1 + q * 256);
        const float4 ve4 = *reinterpret_cast<const float4*>(p2 + q * 256);
        const float4 s04 = *reinterpret_cast<const float4*>(ps + q * 256);
        const float4 t14 = *reinterpret_cast<const float4*>(pt + q * 256);
        const float ktv[4] = {kt4.x, kt4.y, kt4.z, kt4.w};
        const float vpv[4] = {vp4.x, vp4.y, vp4.z, vp4.w};
        const float vev[4] = {ve4.x, ve4.y, ve4.z, ve4.w};
        const float s0v[4] = {s04.x, s04.y, s04.z, s04.w};
        const float t1v[4] = {t14.x, t14.y, t14.z, t14.w};
#pragma unroll
        for (int i = 0; i < 4; ++i) {
            const int j = q * 4 + i;
            const float Ktrans = ktv[i] * (1.0f / 60.0f);
            const float Kep    = __fdividef(Ktrans, vev[i] + EPS);
            Kt[j]    = Ktrans;
            vp[j]    = vpv[i];
            decay[j] = __expf(-Kep * DT);
            const float P = __fdividef(TR, t1v[i] + EPS);
            const float e = __expf(-P);
            eP[j] = e;
            Kc[j] = (1.0f - COS_FA * e) * s0v[i];
            const float den1 = 1.0f - e;
            d0[j] = den1 + EPS;              // den = d0 - d1*ePQ
            d1[j] = COS_FA * den1;
            Ce[j] = 0.0f;
        }
    }

    const float* cp_row = Cp + b * N_TIME;   // uniform -> s_load
    const int t0 = chunk * CHUNK_LEN;

    // Replay the fma-only recurrence up to this chunk's start (<=45 iters).
    for (int t = 0; t < t0; ++t) {
        const float cpdt = cp_row[t] * DT;
#pragma unroll
        for (int j = 0; j < 16; ++j) Ce[j] = Ce[j] * decay[j] + cpdt;
    }

    float* outp = out + ((size_t)(b * N_TIME + t0)) * HW + pixw;

#pragma unroll
    for (int k = 0; k < CHUNK_LEN; ++k) {
        const float cp   = cp_row[t0 + k];
        const float cpdt = cp * DT;
        float* op = outp + (size_t)k * HW;
#pragma unroll
        for (int q = 0; q < 4; ++q) {
            float st[4];
#pragma unroll
            for (int i = 0; i < 4; ++i) {
                const int j = q * 4 + i;
                Ce[j] = Ce[j] * decay[j] + cpdt;
                const float Ct  = vp[j] * cp + Kt[j] * Ce[j];
                const float ePQ = eP[j] * exp2f(-QC2 * Ct);
                const float num = Kc[j] - Kc[j] * ePQ;
                const float den = d0[j] - d1[j] * ePQ;
                st[i] = __fdividef(num, den);
            }
            f32x4 v = {st[0], st[1], st[2], st[3]};
            // Plain allocating store: output (126 MB) fits 256 MB L3.
            *reinterpret_cast<f32x4*>(op + q * 256) = v;
        }
    }
}

extern "C" void kernel_launch(void* const* d_in, const int* in_sizes, int n_in,
                              void* d_out, int out_size, void* d_ws, size_t ws_size,
                              hipStream_t stream) {
    const float* params = (const float*)d_in[0];
    const float* Cp     = (const float*)d_in[1];
    const float* S0     = (const float*)d_in[2];
    const float* T1     = (const float*)d_in[3];
    float* out          = (float*)d_out;

    const int grid = 8 * CHUNKS * (HW / PXB);  // 512 blocks
    etofts_kernel<<<grid, 256, 0, stream>>>(params, Cp, S0, T1, out);
}